// Round 11
// baseline (193.505 us; speedup 1.0000x reference)
//
#include <hip/hip_runtime.h>
#include <math.h>

// Problem constants: B=4, L=2048, d=192, n=64, chunk=128
#define TOK      8192
#define DIM      192
#define NST      64
#define PCHUNK   128
#define NCHUNKS  64
#define CPB      16
#define BATCH    4
#define SUB      16
#define NSUB     8
#define NG       4      // n-groups (2048 blocks in state/intra)
#define NPG      16     // n per group

typedef __attribute__((ext_vector_type(8))) short  bf16x8;
typedef __attribute__((ext_vector_type(4))) float  f32x4;

__device__ __forceinline__ unsigned short f2bf(float f) {
    unsigned int u = __float_as_uint(f);
    u += 0x7fff + ((u >> 16) & 1);          // RNE
    return (unsigned short)(u >> 16);
}
__device__ __forceinline__ float bf2f(unsigned short h) {
    return __uint_as_float(((unsigned int)h) << 16);
}

// ---------------------------------------------------------------------------
// Prep: cast x -> xb ; build bigW[704][192] bf16 (rows 0..383 = W_xp;
// rows 384..703 = [W_B;W_C;W_dt] @ W_xp_top^T) ; woutb ; biasAll[704]
// ---------------------------------------------------------------------------
#define XU      393216                 // TOK*DIM/4
#define WXPU    18432                  // 384*192/4
#define WOUTU   9216                   // 192*192/4
#define CAST_U  (XU + WXPU + WOUTU)
#define FOLD_U  15360                  // 320 rows x 48 k4-units
#define PREP_N  (CAST_U + FOLD_U + 704)

__global__ __launch_bounds__(256)
void prep_kernel(const float* __restrict__ x,   const float* __restrict__ Wxp,
                 const float* __restrict__ WB,  const float* __restrict__ WC,
                 const float* __restrict__ Wdt, const float* __restrict__ Wout,
                 const float* __restrict__ b_xp, const float* __restrict__ b_dt,
                 unsigned short* __restrict__ xb,
                 unsigned short* __restrict__ bigW,
                 unsigned short* __restrict__ woutb,
                 float* __restrict__ biasAll)
{
    int u = blockIdx.x * 256 + threadIdx.x;
    if (u < CAST_U) {
        const float* src; unsigned short* dst; int idx;
        if      (u < XU)        { src = x;    dst = xb;    idx = u; }
        else if (u < XU + WXPU) { src = Wxp;  dst = bigW;  idx = u - XU; }
        else                    { src = Wout; dst = woutb; idx = u - XU - WXPU; }
        float4 v = *(const float4*)(src + (size_t)idx * 4);
        ushort4 r; r.x = f2bf(v.x); r.y = f2bf(v.y); r.z = f2bf(v.z); r.w = f2bf(v.w);
        *(ushort4*)(dst + (size_t)idx * 4) = r;
    } else if (u < CAST_U + FOLD_U) {
        int idx = u - CAST_U;
        int n = idx / 48, k4 = idx % 48;
        const float* wr = (n < 64) ? WB + (size_t)n * DIM
                        : (n < 128) ? WC + (size_t)(n - 64) * DIM
                                    : Wdt + (size_t)(n - 128) * DIM;
        float4 acc = {0.f, 0.f, 0.f, 0.f};
        for (int j = 0; j < DIM; ++j) {
            float w = wr[j];
            float4 xp = *(const float4*)(Wxp + (size_t)j * DIM + k4 * 4);
            acc.x = fmaf(w, xp.x, acc.x); acc.y = fmaf(w, xp.y, acc.y);
            acc.z = fmaf(w, xp.z, acc.z); acc.w = fmaf(w, xp.w, acc.w);
        }
        ushort4 r; r.x = f2bf(acc.x); r.y = f2bf(acc.y); r.z = f2bf(acc.z); r.w = f2bf(acc.w);
        *(ushort4*)(bigW + (size_t)(384 + n) * DIM + k4 * 4) = r;
    } else if (u < PREP_N) {
        int col = u - CAST_U - FOLD_U;
        if (col < 384) { biasAll[col] = b_xp[col]; return; }
        int n = col - 384;
        const float* wr = (n < 64) ? WB + (size_t)n * DIM
                        : (n < 128) ? WC + (size_t)(n - 64) * DIM
                                    : Wdt + (size_t)(n - 128) * DIM;
        float a0 = 0.f, a1 = 0.f, a2 = 0.f, a3 = 0.f;
        for (int j = 0; j < DIM; j += 4) {
            a0 = fmaf(wr[j+0], b_xp[j+0], a0);
            a1 = fmaf(wr[j+1], b_xp[j+1], a1);
            a2 = fmaf(wr[j+2], b_xp[j+2], a2);
            a3 = fmaf(wr[j+3], b_xp[j+3], a3);
        }
        float acc = (a0 + a1) + (a2 + a3);
        if (n >= 128) acc += b_dt[n - 128];
        biasAll[col] = acc;
    }
}

// ---------------------------------------------------------------------------
// ONE fused projection GEMM: xb @ bigW^T + biasAll, 704 cols.
// Wave tile 16x64; block 64 rows; grid (128, 11) = 1408 blocks.
//   n0<192: xbarb bf16 | n0<384: zarrb bf16 | n0<512: BC fp32 | else: Abarb bf16
// ---------------------------------------------------------------------------
__global__ __launch_bounds__(256)
void gemm_all(const unsigned short* __restrict__ xb,
              const unsigned short* __restrict__ bigW,
              const float* __restrict__ biasAll, const float* __restrict__ A_log,
              unsigned short* __restrict__ xbarb, unsigned short* __restrict__ zarrb,
              float* __restrict__ BC, unsigned short* __restrict__ Abarb)
{
    const int lane = threadIdx.x & 63, wave = threadIdx.x >> 6;
    const int m0 = blockIdx.x * 64 + wave * 16;
    const int n0 = blockIdx.y * 64;
    const int lr = lane & 15, kg = lane >> 4;
    f32x4 acc[4] = {};
    for (int k0 = 0; k0 < DIM; k0 += 32) {
        bf16x8 af = *(const bf16x8*)(xb + (size_t)(m0 + lr) * DIM + k0 + kg*8);
        bf16x8 bfr[4];
        #pragma unroll
        for (int ni = 0; ni < 4; ++ni)
            bfr[ni] = *(const bf16x8*)(bigW + (size_t)(n0 + ni*16 + lr) * DIM + k0 + kg*8);
        #pragma unroll
        for (int ni = 0; ni < 4; ++ni)
            acc[ni] = __builtin_amdgcn_mfma_f32_16x16x32_bf16(af, bfr[ni], acc[ni], 0, 0, 0);
    }
    if (n0 < 384) {                      // xbar or z (bf16)
        unsigned short* dst = (n0 < 192) ? xbarb : zarrb;
        int cofs = (n0 < 192) ? 0 : 192;
        #pragma unroll
        for (int ni = 0; ni < 4; ++ni) {
            int col = n0 + ni*16 + lr;
            float bias = biasAll[col];
            #pragma unroll
            for (int r = 0; r < 4; ++r) {
                int row = m0 + kg*4 + r;
                dst[(size_t)row * DIM + col - cofs] = f2bf(acc[ni][r] + bias);
            }
        }
    } else if (n0 < 512) {               // BC fp32
        #pragma unroll
        for (int ni = 0; ni < 4; ++ni) {
            int col = n0 + ni*16 + lr;
            float bias = biasAll[col];
            #pragma unroll
            for (int r = 0; r < 4; ++r) {
                int row = m0 + kg*4 + r;
                BC[(size_t)row * 128 + col - 384] = acc[ni][r] + bias;
            }
        }
    } else {                             // Abar bf16
        #pragma unroll
        for (int ni = 0; ni < 4; ++ni) {
            int col = n0 + ni*16 + lr;
            int c2 = col - 512;
            float bias = biasAll[col];
            float Av = -expf(A_log[c2]);
            #pragma unroll
            for (int r = 0; r < 4; ++r) {
                int row = m0 + kg*4 + r;
                float v = acc[ni][r] + bias;
                float sp = (v > 20.f) ? v : log1pf(expf(v));
                Abarb[(size_t)row * DIM + c2] = f2bf(expf(sp * Av));
            }
        }
    }
}

// ---------------------------------------------------------------------------
// out = y_g @ W_out^T + b_out. Wave tile 16x64; grid (128, 3) = 384 blocks.
// ---------------------------------------------------------------------------
__global__ __launch_bounds__(256)
void out_gemm(const unsigned short* __restrict__ ygb,
              const unsigned short* __restrict__ woutb,
              const float* __restrict__ b_out, float* __restrict__ out)
{
    const int lane = threadIdx.x & 63, wave = threadIdx.x >> 6;
    const int m0 = blockIdx.x * 64 + wave * 16;
    const int n0 = blockIdx.y * 64;
    const int lr = lane & 15, kg = lane >> 4;
    f32x4 acc[4] = {};
    for (int k0 = 0; k0 < DIM; k0 += 32) {
        bf16x8 af = *(const bf16x8*)(ygb + (size_t)(m0 + lr) * DIM + k0 + kg*8);
        bf16x8 bfr[4];
        #pragma unroll
        for (int ni = 0; ni < 4; ++ni)
            bfr[ni] = *(const bf16x8*)(woutb + (size_t)(n0 + ni*16 + lr) * DIM + k0 + kg*8);
        #pragma unroll
        for (int ni = 0; ni < 4; ++ni)
            acc[ni] = __builtin_amdgcn_mfma_f32_16x16x32_bf16(af, bfr[ni], acc[ni], 0, 0, 0);
    }
    #pragma unroll
    for (int ni = 0; ni < 4; ++ni) {
        int col = n0 + ni*16 + lr;
        float bias = b_out[col];
        #pragma unroll
        for (int r = 0; r < 4; ++r) {
            int row = m0 + kg*4 + r;
            out[(size_t)row * DIM + col] = acc[ni][r] + bias;
        }
    }
}

// ---------------------------------------------------------------------------
// Fused sub-state + chunk-state partial. Grid (64, 8 subs, 4 g), 192 thr.
// 16-step serial loop; 2048 blocks = 24/32 waves/CU.
// ---------------------------------------------------------------------------
__global__ __launch_bounds__(192)
void state_kernel(const unsigned short* __restrict__ xbarb,
                  const unsigned short* __restrict__ Abarb,
                  const float* __restrict__ Bm,      // BC, stride 128 (B cols 0..63)
                  float* __restrict__ S,
                  float* __restrict__ R,
                  float* __restrict__ dprod)
{
    int bc = blockIdx.x, s = blockIdx.y, g = blockIdx.z;
    int dd = threadIdx.x;
    int t0 = bc * PCHUNK + s * SUB;
    __shared__ float Bs[SUB][NPG];
    if (threadIdx.x < SUB * NPG / 4) {          // 64 float4 units
        int row = threadIdx.x >> 2, c4 = threadIdx.x & 3;
        *(float4*)&Bs[row][c4 * 4] =
            *(const float4*)(Bm + (size_t)(t0 + row) * 128 + g * NPG + c4 * 4);
    }
    __syncthreads();
    float H[NPG] = {}, Rr[NPG] = {};
    float cp = 1.f;
    float a_cur = bf2f(Abarb[(size_t)t0 * DIM + dd]) + 1e-8f;
    float x_cur = bf2f(xbarb[(size_t)t0 * DIM + dd]);
    for (int i = 0; i < SUB; ++i) {
        float a_nxt = 0.f, x_nxt = 0.f;
        if (i + 1 < SUB) {
            a_nxt = bf2f(Abarb[(size_t)(t0 + i + 1) * DIM + dd]) + 1e-8f;
            x_nxt = bf2f(xbarb[(size_t)(t0 + i + 1) * DIM + dd]);
        }
        cp *= a_cur;
        float4 b0 = *(const float4*)&Bs[i][0];
        float4 b1 = *(const float4*)&Bs[i][4];
        float4 b2 = *(const float4*)&Bs[i][8];
        float4 b3 = *(const float4*)&Bs[i][12];
        float bb[NPG] = {b0.x,b0.y,b0.z,b0.w, b1.x,b1.y,b1.z,b1.w,
                         b2.x,b2.y,b2.z,b2.w, b3.x,b3.y,b3.z,b3.w};
        #pragma unroll
        for (int j = 0; j < NPG; ++j) {
            float u = bb[j] * x_cur;
            H[j]  = fmaf(a_cur, H[j], u);
            Rr[j] = fmaf(u, a_cur, Rr[j]);
        }
        a_cur = a_nxt; x_cur = x_nxt;
    }
    size_t base = (((size_t)(bc * NSUB + s)) * NST + g * NPG) * DIM + dd;
    #pragma unroll
    for (int j = 0; j < NPG; ++j) {
        S[base + (size_t)j * DIM] = H[j];
        R[base + (size_t)j * DIM] = Rr[j];
    }
    if (g == 0) dprod[(size_t)(bc * NSUB + s) * DIM + dd] = cp;
}

// ---------------------------------------------------------------------------
// Inter-chunk scan with inline per-chunk reduction over 8 sub-partials.
// ---------------------------------------------------------------------------
__global__ __launch_bounds__(256)
void scan_kernel(const float* __restrict__ dprod,
                 const float* __restrict__ R,
                 float* __restrict__ prev)
{
    int v = blockIdx.x * 256 + threadIdx.x;
    if (v >= BATCH * NST * 48) return;
    int dd = (v % 48) * 4;
    int nn = (v / 48) % NST;
    int b  = v / (48 * NST);
    int bc0 = b * CPB;
    const size_t Q2 = (size_t)NST * DIM;
    float4 st = {0.f, 0.f, 0.f, 0.f};
    for (int c = 0; c < CPB; ++c) {
        int bc = bc0 + c;
        size_t so = ((size_t)(bc * NSUB) * NST + nn) * DIM + dd;
        size_t po = (size_t)(bc * NSUB) * DIM + dd;
        float4 Rs = {0.f, 0.f, 0.f, 0.f};
        float4 cA = {1.f, 1.f, 1.f, 1.f};
        #pragma unroll
        for (int s = 0; s < NSUB; ++s) {
            float4 rv = *(const float4*)(R + so + (size_t)s * Q2);
            float4 dv = *(const float4*)(dprod + po + (size_t)s * DIM);
            Rs.x += rv.x; Rs.y += rv.y; Rs.z += rv.z; Rs.w += rv.w;
            cA.x *= dv.x; cA.y *= dv.y; cA.z *= dv.z; cA.w *= dv.w;
        }
        *(float4*)(prev + ((size_t)bc * NST + nn) * DIM + dd) = st;
        st.x = fmaf(st.x, cA.x, Rs.x);
        st.y = fmaf(st.y, cA.y, Rs.y);
        st.z = fmaf(st.z, cA.z, Rs.z);
        st.w = fmaf(st.w, cA.w, Rs.w);
    }
}

// ---------------------------------------------------------------------------
// Intra recurrence. H seeded with inline carry scan over earlier sub-chunks.
// Grid (64, 8 subs, 4 g), 192 thr. p_y written bf16 (4 partials).
// ---------------------------------------------------------------------------
__global__ __launch_bounds__(192)
void intra_kernel(const unsigned short* __restrict__ xbarb,
                  const unsigned short* __restrict__ Abarb,
                  const float* __restrict__ BC,     // stride 128; B 0..63, C 64..127
                  const float* __restrict__ prev,
                  const float* __restrict__ S,
                  const float* __restrict__ dprod,
                  unsigned short* __restrict__ p_y)
{
    int bc = blockIdx.x, s = blockIdx.y, g = blockIdx.z;
    int dd = threadIdx.x;
    int t0 = bc * PCHUNK + s * SUB;
    __shared__ float Bs[SUB][NPG];
    __shared__ float Cs[SUB][NPG];
    {
        int nunits = SUB * NPG / 4;             // 64 per matrix
        for (int idx = threadIdx.x; idx < 2 * nunits; idx += 192) {
            int m = idx >= nunits;
            int q = idx - m * nunits;
            int row = q >> 2, c4 = q & 3;
            const float* src = BC + (size_t)(t0 + row) * 128
                             + (m ? 64 : 0) + g * NPG + c4 * 4;
            float4 v = *(const float4*)src;
            if (m) *(float4*)&Cs[row][c4 * 4] = v;
            else   *(float4*)&Bs[row][c4 * 4] = v;
        }
    }
    float H[NPG] = {}, P[NPG];
    for (int k = 0; k < s; ++k) {
        float dpk = dprod[(size_t)(bc * NSUB + k) * DIM + dd];
        size_t sb = (((size_t)(bc * NSUB + k)) * NST + g * NPG) * DIM + dd;
        #pragma unroll
        for (int j = 0; j < NPG; ++j)
            H[j] = fmaf(H[j], dpk, S[sb + (size_t)j * DIM]);
    }
    #pragma unroll
    for (int j = 0; j < NPG; ++j)
        P[j] = prev[((size_t)bc * NST + g * NPG + j) * DIM + dd];
    __syncthreads();

    float a_cur = bf2f(Abarb[(size_t)t0 * DIM + dd]) + 1e-8f;
    float x_cur = bf2f(xbarb[(size_t)t0 * DIM + dd]);
    for (int i = 0; i < SUB; ++i) {
        int t = t0 + i;
        float a_nxt = 0.f, x_nxt = 0.f;
        if (i + 1 < SUB) {
            a_nxt = bf2f(Abarb[(size_t)(t + 1) * DIM + dd]) + 1e-8f;
            x_nxt = bf2f(xbarb[(size_t)(t + 1) * DIM + dd]);
        }
        float4 b0 = *(const float4*)&Bs[i][0];
        float4 b1 = *(const float4*)&Bs[i][4];
        float4 b2 = *(const float4*)&Bs[i][8];
        float4 b3 = *(const float4*)&Bs[i][12];
        float4 c0 = *(const float4*)&Cs[i][0];
        float4 c1 = *(const float4*)&Cs[i][4];
        float4 c2 = *(const float4*)&Cs[i][8];
        float4 c3 = *(const float4*)&Cs[i][12];
        float bb[NPG] = {b0.x,b0.y,b0.z,b0.w, b1.x,b1.y,b1.z,b1.w,
                         b2.x,b2.y,b2.z,b2.w, b3.x,b3.y,b3.z,b3.w};
        float cc[NPG] = {c0.x,c0.y,c0.z,c0.w, c1.x,c1.y,c1.z,c1.w,
                         c2.x,c2.y,c2.z,c2.w, c3.x,c3.y,c3.z,c3.w};
        float ya[4] = {0.f, 0.f, 0.f, 0.f};
        #pragma unroll
        for (int j = 0; j < NPG; ++j) {
            H[j] = fmaf(a_cur, H[j], bb[j] * x_cur);
            ya[j & 3] = fmaf(cc[j], H[j] + P[j], ya[j & 3]);
        }
        p_y[((size_t)g * TOK + t) * DIM + dd] = f2bf((ya[0] + ya[1]) + (ya[2] + ya[3]));
        a_cur = a_nxt; x_cur = x_nxt;
    }
}

// y_g = (sum of 4 bf16 partials) * silu(z)  -> bf16
__global__ __launch_bounds__(256)
void gate_kernel(const unsigned short* __restrict__ p_y,
                 const unsigned short* __restrict__ zarrb,
                 unsigned short* __restrict__ ygb)
{
    int v = blockIdx.x * 256 + threadIdx.x;
    if (v >= TOK * 48) return;
    int t = v / 48;
    int dd = (v % 48) * 4;
    const size_t Q = (size_t)TOK * DIM;
    size_t off = (size_t)t * DIM + dd;
    float acc[4] = {0.f, 0.f, 0.f, 0.f};
    #pragma unroll
    for (int gidx = 0; gidx < NG; ++gidx) {
        ushort4 y = *(const ushort4*)(p_y + off + (size_t)gidx * Q);
        acc[0] += bf2f(y.x); acc[1] += bf2f(y.y);
        acc[2] += bf2f(y.z); acc[3] += bf2f(y.w);
    }
    ushort4 zu = *(const ushort4*)(zarrb + off);
    float z0 = bf2f(zu.x), z1 = bf2f(zu.y), z2 = bf2f(zu.z), z3 = bf2f(zu.w);
    ushort4 r;
    r.x = f2bf(acc[0] * (z0 / (1.f + expf(-z0))));
    r.y = f2bf(acc[1] * (z1 / (1.f + expf(-z1))));
    r.z = f2bf(acc[2] * (z2 / (1.f + expf(-z2))));
    r.w = f2bf(acc[3] * (z3 / (1.f + expf(-z3))));
    *(ushort4*)(ygb + off) = r;
}

// ---------------------------------------------------------------------------
extern "C" void kernel_launch(void* const* d_in, const int* in_sizes, int n_in,
                              void* d_out, int out_size, void* d_ws, size_t ws_size,
                              hipStream_t stream)
{
    (void)in_sizes; (void)n_in; (void)out_size; (void)ws_size;
    const float* x     = (const float*)d_in[0];
    const float* A_log = (const float*)d_in[1];
    const float* W_B   = (const float*)d_in[2];
    const float* W_C   = (const float*)d_in[3];
    const float* W_dt  = (const float*)d_in[4];
    const float* b_dt  = (const float*)d_in[5];
    const float* W_xp  = (const float*)d_in[6];
    const float* b_xp  = (const float*)d_in[7];
    const float* W_out = (const float*)d_in[8];
    const float* b_out = (const float*)d_in[9];
    float* out = (float*)d_out;

    char* w = (char*)d_ws;
    auto take = [&](size_t bytes) { char* p = w; w += (bytes + 255) & ~(size_t)255; return p; };
    unsigned short* xb     = (unsigned short*)take((size_t)TOK*DIM*2);
    unsigned short* bigW   = (unsigned short*)take((size_t)704*DIM*2);
    unsigned short* woutb  = (unsigned short*)take((size_t)DIM*DIM*2);
    float*          biasAll= (float*)         take((size_t)704*4);
    unsigned short* xbarb  = (unsigned short*)take((size_t)TOK*DIM*2);
    unsigned short* zarrb  = (unsigned short*)take((size_t)TOK*DIM*2);
    float*          BC     = (float*)         take((size_t)TOK*128*4);
    unsigned short* Abarb  = (unsigned short*)take((size_t)TOK*DIM*2);
    float*          dprod  = (float*)         take((size_t)NCHUNKS*NSUB*DIM*4);
    float*          prev   = (float*)         take((size_t)NCHUNKS*NST*DIM*4);
    float*          Sarr   = (float*)         take((size_t)NCHUNKS*NSUB*NST*DIM*4);
    float*          Rarr   = (float*)         take((size_t)NCHUNKS*NSUB*NST*DIM*4);
    unsigned short* p_y    = (unsigned short*)take((size_t)NG*TOK*DIM*2);
    unsigned short* ygb    = (unsigned short*)take((size_t)TOK*DIM*2);

    dim3 blk(256);

    prep_kernel<<<dim3((PREP_N + 255)/256), blk, 0, stream>>>(
        x, W_xp, W_B, W_C, W_dt, W_out, b_xp, b_dt, xb, bigW, woutb, biasAll);
    gemm_all<<<dim3(TOK/64, 704/64), blk, 0, stream>>>(
        xb, bigW, biasAll, A_log, xbarb, zarrb, BC, Abarb);
    state_kernel<<<dim3(NCHUNKS, NSUB, NG), dim3(192), 0, stream>>>(
        xbarb, Abarb, BC, Sarr, Rarr, dprod);
    scan_kernel<<<dim3((BATCH*NST*48 + 255)/256), blk, 0, stream>>>(dprod, Rarr, prev);
    intra_kernel<<<dim3(NCHUNKS, NSUB, NG), dim3(192), 0, stream>>>(
        xbarb, Abarb, BC, prev, Sarr, dprod, p_y);
    gate_kernel<<<dim3((TOK*48 + 255)/256), blk, 0, stream>>>(p_y, zarrb, ygb);
    out_gemm<<<dim3(TOK/64, DIM/64), blk, 0, stream>>>(ygb, woutb, b_out, out);
}

// Round 12
// 174.603 us; speedup vs baseline: 1.1083x; 1.1083x over previous
//
#include <hip/hip_runtime.h>
#include <math.h>

// Problem constants: B=4, L=2048, d=192, n=64, chunk=128
#define TOK      8192
#define DIM      192
#define NST      64
#define PCHUNK   128
#define NCHUNKS  64
#define CPB      16
#define BATCH    4
#define SUB      32
#define NSUB     4
#define NG       4      // n-groups (1024 blocks in state/intra)
#define NPG      16     // n per group

typedef __attribute__((ext_vector_type(8))) short  bf16x8;
typedef __attribute__((ext_vector_type(4))) float  f32x4;

__device__ __forceinline__ unsigned short f2bf(float f) {
    unsigned int u = __float_as_uint(f);
    u += 0x7fff + ((u >> 16) & 1);          // RNE
    return (unsigned short)(u >> 16);
}
__device__ __forceinline__ float bf2f(unsigned short h) {
    return __uint_as_float(((unsigned int)h) << 16);
}

// ---------------------------------------------------------------------------
// Prep: cast x -> xb ; build bigW[704][192] bf16 (rows 0..383 = W_xp;
// rows 384..703 = [W_B;W_C;W_dt] @ W_xp_top^T) ; woutb ; biasAll[704]
// ---------------------------------------------------------------------------
#define XU      393216                 // TOK*DIM/4
#define WXPU    18432                  // 384*192/4
#define WOUTU   9216                   // 192*192/4
#define CAST_U  (XU + WXPU + WOUTU)
#define FOLD_U  15360                  // 320 rows x 48 k4-units
#define PREP_N  (CAST_U + FOLD_U + 704)

__global__ __launch_bounds__(256)
void prep_kernel(const float* __restrict__ x,   const float* __restrict__ Wxp,
                 const float* __restrict__ WB,  const float* __restrict__ WC,
                 const float* __restrict__ Wdt, const float* __restrict__ Wout,
                 const float* __restrict__ b_xp, const float* __restrict__ b_dt,
                 unsigned short* __restrict__ xb,
                 unsigned short* __restrict__ bigW,
                 unsigned short* __restrict__ woutb,
                 float* __restrict__ biasAll)
{
    int u = blockIdx.x * 256 + threadIdx.x;
    if (u < CAST_U) {
        const float* src; unsigned short* dst; int idx;
        if      (u < XU)        { src = x;    dst = xb;    idx = u; }
        else if (u < XU + WXPU) { src = Wxp;  dst = bigW;  idx = u - XU; }
        else                    { src = Wout; dst = woutb; idx = u - XU - WXPU; }
        float4 v = *(const float4*)(src + (size_t)idx * 4);
        ushort4 r; r.x = f2bf(v.x); r.y = f2bf(v.y); r.z = f2bf(v.z); r.w = f2bf(v.w);
        *(ushort4*)(dst + (size_t)idx * 4) = r;
    } else if (u < CAST_U + FOLD_U) {
        int idx = u - CAST_U;
        int n = idx / 48, k4 = idx % 48;
        const float* wr = (n < 64) ? WB + (size_t)n * DIM
                        : (n < 128) ? WC + (size_t)(n - 64) * DIM
                                    : Wdt + (size_t)(n - 128) * DIM;
        float4 acc = {0.f, 0.f, 0.f, 0.f};
        for (int j = 0; j < DIM; ++j) {
            float w = wr[j];
            float4 xp = *(const float4*)(Wxp + (size_t)j * DIM + k4 * 4);
            acc.x = fmaf(w, xp.x, acc.x); acc.y = fmaf(w, xp.y, acc.y);
            acc.z = fmaf(w, xp.z, acc.z); acc.w = fmaf(w, xp.w, acc.w);
        }
        ushort4 r; r.x = f2bf(acc.x); r.y = f2bf(acc.y); r.z = f2bf(acc.z); r.w = f2bf(acc.w);
        *(ushort4*)(bigW + (size_t)(384 + n) * DIM + k4 * 4) = r;
    } else if (u < PREP_N) {
        int col = u - CAST_U - FOLD_U;
        if (col < 384) { biasAll[col] = b_xp[col]; return; }
        int n = col - 384;
        const float* wr = (n < 64) ? WB + (size_t)n * DIM
                        : (n < 128) ? WC + (size_t)(n - 64) * DIM
                                    : Wdt + (size_t)(n - 128) * DIM;
        float a0 = 0.f, a1 = 0.f, a2 = 0.f, a3 = 0.f;
        for (int j = 0; j < DIM; j += 4) {
            a0 = fmaf(wr[j+0], b_xp[j+0], a0);
            a1 = fmaf(wr[j+1], b_xp[j+1], a1);
            a2 = fmaf(wr[j+2], b_xp[j+2], a2);
            a3 = fmaf(wr[j+3], b_xp[j+3], a3);
        }
        float acc = (a0 + a1) + (a2 + a3);
        if (n >= 128) acc += b_dt[n - 128];
        biasAll[col] = acc;
    }
}

// ---------------------------------------------------------------------------
// ONE fused projection GEMM: xb @ bigW^T + biasAll, 704 cols.
// Wave tile 32x64 (2 m-frags); block 128 rows; grid (64, 11) = 704 blocks.
//   n0<192: xbarb bf16 | n0<384: zarrb bf16 | n0<512: BC fp32 | else: Abarb bf16
// ---------------------------------------------------------------------------
__global__ __launch_bounds__(256)
void gemm_all(const unsigned short* __restrict__ xb,
              const unsigned short* __restrict__ bigW,
              const float* __restrict__ biasAll, const float* __restrict__ A_log,
              unsigned short* __restrict__ xbarb, unsigned short* __restrict__ zarrb,
              float* __restrict__ BC, unsigned short* __restrict__ Abarb)
{
    const int lane = threadIdx.x & 63, wave = threadIdx.x >> 6;
    const int m_wave = blockIdx.x * 128 + wave * 32;
    const int n0 = blockIdx.y * 64;
    const int lr = lane & 15, kg = lane >> 4;
    f32x4 acc[2][4] = {};
    for (int k0 = 0; k0 < DIM; k0 += 32) {
        bf16x8 af[2], bfr[4];
        #pragma unroll
        for (int mi = 0; mi < 2; ++mi)
            af[mi] = *(const bf16x8*)(xb + (size_t)(m_wave + mi*16 + lr) * DIM + k0 + kg*8);
        #pragma unroll
        for (int ni = 0; ni < 4; ++ni)
            bfr[ni] = *(const bf16x8*)(bigW + (size_t)(n0 + ni*16 + lr) * DIM + k0 + kg*8);
        #pragma unroll
        for (int mi = 0; mi < 2; ++mi)
            #pragma unroll
            for (int ni = 0; ni < 4; ++ni)
                acc[mi][ni] = __builtin_amdgcn_mfma_f32_16x16x32_bf16(
                                  af[mi], bfr[ni], acc[mi][ni], 0, 0, 0);
    }
    if (n0 < 384) {                      // xbar or z (bf16)
        unsigned short* dst = (n0 < 192) ? xbarb : zarrb;
        int cofs = (n0 < 192) ? 0 : 192;
        #pragma unroll
        for (int ni = 0; ni < 4; ++ni) {
            int col = n0 + ni*16 + lr;
            float bias = biasAll[col];
            #pragma unroll
            for (int mi = 0; mi < 2; ++mi)
                #pragma unroll
                for (int r = 0; r < 4; ++r) {
                    int row = m_wave + mi*16 + kg*4 + r;
                    dst[(size_t)row * DIM + col - cofs] = f2bf(acc[mi][ni][r] + bias);
                }
        }
    } else if (n0 < 512) {               // BC fp32
        #pragma unroll
        for (int ni = 0; ni < 4; ++ni) {
            int col = n0 + ni*16 + lr;
            float bias = biasAll[col];
            #pragma unroll
            for (int mi = 0; mi < 2; ++mi)
                #pragma unroll
                for (int r = 0; r < 4; ++r) {
                    int row = m_wave + mi*16 + kg*4 + r;
                    BC[(size_t)row * 128 + col - 384] = acc[mi][ni][r] + bias;
                }
        }
    } else {                             // Abar bf16
        #pragma unroll
        for (int ni = 0; ni < 4; ++ni) {
            int col = n0 + ni*16 + lr;
            int c2 = col - 512;
            float bias = biasAll[col];
            float Av = -expf(A_log[c2]);
            #pragma unroll
            for (int mi = 0; mi < 2; ++mi)
                #pragma unroll
                for (int r = 0; r < 4; ++r) {
                    int row = m_wave + mi*16 + kg*4 + r;
                    float v = acc[mi][ni][r] + bias;
                    float sp = (v > 20.f) ? v : log1pf(expf(v));
                    Abarb[(size_t)row * DIM + c2] = f2bf(expf(sp * Av));
                }
        }
    }
}

// ---------------------------------------------------------------------------
// out = y_g @ W_out^T + b_out. Wave tile 16x64; grid (128, 3) = 384 blocks.
// ---------------------------------------------------------------------------
__global__ __launch_bounds__(256)
void out_gemm(const unsigned short* __restrict__ ygb,
              const unsigned short* __restrict__ woutb,
              const float* __restrict__ b_out, float* __restrict__ out)
{
    const int lane = threadIdx.x & 63, wave = threadIdx.x >> 6;
    const int m0 = blockIdx.x * 64 + wave * 16;
    const int n0 = blockIdx.y * 64;
    const int lr = lane & 15, kg = lane >> 4;
    f32x4 acc[4] = {};
    for (int k0 = 0; k0 < DIM; k0 += 32) {
        bf16x8 af = *(const bf16x8*)(ygb + (size_t)(m0 + lr) * DIM + k0 + kg*8);
        bf16x8 bfr[4];
        #pragma unroll
        for (int ni = 0; ni < 4; ++ni)
            bfr[ni] = *(const bf16x8*)(woutb + (size_t)(n0 + ni*16 + lr) * DIM + k0 + kg*8);
        #pragma unroll
        for (int ni = 0; ni < 4; ++ni)
            acc[ni] = __builtin_amdgcn_mfma_f32_16x16x32_bf16(af, bfr[ni], acc[ni], 0, 0, 0);
    }
    #pragma unroll
    for (int ni = 0; ni < 4; ++ni) {
        int col = n0 + ni*16 + lr;
        float bias = b_out[col];
        #pragma unroll
        for (int r = 0; r < 4; ++r) {
            int row = m0 + kg*4 + r;
            out[(size_t)row * DIM + col] = acc[ni][r] + bias;
        }
    }
}

// ---------------------------------------------------------------------------
// Fused sub-state + chunk-state partial. Grid (64, 4 subs, 4 g), 192 thr.
// ---------------------------------------------------------------------------
__global__ __launch_bounds__(192)
void state_kernel(const unsigned short* __restrict__ xbarb,
                  const unsigned short* __restrict__ Abarb,
                  const float* __restrict__ Bm,      // BC, stride 128 (B cols 0..63)
                  float* __restrict__ S,
                  float* __restrict__ R,
                  float* __restrict__ dprod)
{
    int bc = blockIdx.x, s = blockIdx.y, g = blockIdx.z;
    int dd = threadIdx.x;
    int t0 = bc * PCHUNK + s * SUB;
    __shared__ float Bs[SUB][NPG];
    if (threadIdx.x < SUB * NPG / 4) {
        int row = threadIdx.x >> 2, c4 = threadIdx.x & 3;
        *(float4*)&Bs[row][c4 * 4] =
            *(const float4*)(Bm + (size_t)(t0 + row) * 128 + g * NPG + c4 * 4);
    }
    __syncthreads();
    float H[NPG] = {}, Rr[NPG] = {};
    float cp = 1.f;
    float a_cur = bf2f(Abarb[(size_t)t0 * DIM + dd]) + 1e-8f;
    float x_cur = bf2f(xbarb[(size_t)t0 * DIM + dd]);
    for (int i = 0; i < SUB; ++i) {
        float a_nxt = 0.f, x_nxt = 0.f;
        if (i + 1 < SUB) {
            a_nxt = bf2f(Abarb[(size_t)(t0 + i + 1) * DIM + dd]) + 1e-8f;
            x_nxt = bf2f(xbarb[(size_t)(t0 + i + 1) * DIM + dd]);
        }
        cp *= a_cur;
        float4 b0 = *(const float4*)&Bs[i][0];
        float4 b1 = *(const float4*)&Bs[i][4];
        float4 b2 = *(const float4*)&Bs[i][8];
        float4 b3 = *(const float4*)&Bs[i][12];
        float bb[NPG] = {b0.x,b0.y,b0.z,b0.w, b1.x,b1.y,b1.z,b1.w,
                         b2.x,b2.y,b2.z,b2.w, b3.x,b3.y,b3.z,b3.w};
        #pragma unroll
        for (int j = 0; j < NPG; ++j) {
            float u = bb[j] * x_cur;
            H[j]  = fmaf(a_cur, H[j], u);
            Rr[j] = fmaf(u, a_cur, Rr[j]);
        }
        a_cur = a_nxt; x_cur = x_nxt;
    }
    size_t base = (((size_t)(bc * NSUB + s)) * NST + g * NPG) * DIM + dd;
    #pragma unroll
    for (int j = 0; j < NPG; ++j) {
        S[base + (size_t)j * DIM] = H[j];
        R[base + (size_t)j * DIM] = Rr[j];
    }
    if (g == 0) dprod[(size_t)(bc * NSUB + s) * DIM + dd] = cp;
}

// ---------------------------------------------------------------------------
// Inter-chunk scan with inline per-chunk reduction (cA, Rsum) + prefetch.
// ---------------------------------------------------------------------------
__global__ __launch_bounds__(256)
void scan_kernel(const float* __restrict__ dprod,
                 const float* __restrict__ R,
                 float* __restrict__ prev)
{
    int v = blockIdx.x * 256 + threadIdx.x;
    if (v >= BATCH * NST * 48) return;
    int dd = (v % 48) * 4;
    int nn = (v / 48) % NST;
    int b  = v / (48 * NST);
    int bc0 = b * CPB;
    const size_t Q2 = (size_t)NST * DIM;
    float4 rv[NSUB], dv[NSUB];
    {
        size_t so = ((size_t)(bc0 * NSUB) * NST + nn) * DIM + dd;
        size_t po = (size_t)(bc0 * NSUB) * DIM + dd;
        #pragma unroll
        for (int s = 0; s < NSUB; ++s) {
            rv[s] = *(const float4*)(R + so + (size_t)s * Q2);
            dv[s] = *(const float4*)(dprod + po + (size_t)s * DIM);
        }
    }
    float4 st = {0.f, 0.f, 0.f, 0.f};
    for (int c = 0; c < CPB; ++c) {
        int bc = bc0 + c;
        float4 rn[NSUB], dn[NSUB];
        if (c + 1 < CPB) {
            size_t so = ((size_t)((bc + 1) * NSUB) * NST + nn) * DIM + dd;
            size_t po = (size_t)((bc + 1) * NSUB) * DIM + dd;
            #pragma unroll
            for (int s = 0; s < NSUB; ++s) {
                rn[s] = *(const float4*)(R + so + (size_t)s * Q2);
                dn[s] = *(const float4*)(dprod + po + (size_t)s * DIM);
            }
        }
        float4 Rs, cA;
        Rs.x = (rv[0].x + rv[1].x) + (rv[2].x + rv[3].x);
        Rs.y = (rv[0].y + rv[1].y) + (rv[2].y + rv[3].y);
        Rs.z = (rv[0].z + rv[1].z) + (rv[2].z + rv[3].z);
        Rs.w = (rv[0].w + rv[1].w) + (rv[2].w + rv[3].w);
        cA.x = (dv[0].x * dv[1].x) * (dv[2].x * dv[3].x);
        cA.y = (dv[0].y * dv[1].y) * (dv[2].y * dv[3].y);
        cA.z = (dv[0].z * dv[1].z) * (dv[2].z * dv[3].z);
        cA.w = (dv[0].w * dv[1].w) * (dv[2].w * dv[3].w);
        *(float4*)(prev + ((size_t)bc * NST + nn) * DIM + dd) = st;
        st.x = fmaf(st.x, cA.x, Rs.x);
        st.y = fmaf(st.y, cA.y, Rs.y);
        st.z = fmaf(st.z, cA.z, Rs.z);
        st.w = fmaf(st.w, cA.w, Rs.w);
        #pragma unroll
        for (int s = 0; s < NSUB; ++s) { rv[s] = rn[s]; dv[s] = dn[s]; }
    }
}

// ---------------------------------------------------------------------------
// Intra recurrence. H seeded with inline carry scan over earlier sub-chunks.
// Grid (64, 4 subs, 4 g), 192 thr. p_y written bf16 (4 partials).
// ---------------------------------------------------------------------------
__global__ __launch_bounds__(192)
void intra_kernel(const unsigned short* __restrict__ xbarb,
                  const unsigned short* __restrict__ Abarb,
                  const float* __restrict__ BC,     // stride 128; B 0..63, C 64..127
                  const float* __restrict__ prev,
                  const float* __restrict__ S,
                  const float* __restrict__ dprod,
                  unsigned short* __restrict__ p_y)
{
    int bc = blockIdx.x, s = blockIdx.y, g = blockIdx.z;
    int dd = threadIdx.x;
    int t0 = bc * PCHUNK + s * SUB;
    __shared__ float Bs[SUB][NPG];
    __shared__ float Cs[SUB][NPG];
    {
        int nunits = SUB * NPG / 4;             // 128 per matrix
        for (int idx = threadIdx.x; idx < 2 * nunits; idx += 192) {
            int m = idx >= nunits;
            int q = idx - m * nunits;
            int row = q >> 2, c4 = q & 3;
            const float* src = BC + (size_t)(t0 + row) * 128
                             + (m ? 64 : 0) + g * NPG + c4 * 4;
            float4 v = *(const float4*)src;
            if (m) *(float4*)&Cs[row][c4 * 4] = v;
            else   *(float4*)&Bs[row][c4 * 4] = v;
        }
    }
    float H[NPG] = {}, P[NPG];
    for (int k = 0; k < s; ++k) {
        float dpk = dprod[(size_t)(bc * NSUB + k) * DIM + dd];
        size_t sb = (((size_t)(bc * NSUB + k)) * NST + g * NPG) * DIM + dd;
        #pragma unroll
        for (int j = 0; j < NPG; ++j)
            H[j] = fmaf(H[j], dpk, S[sb + (size_t)j * DIM]);
    }
    #pragma unroll
    for (int j = 0; j < NPG; ++j)
        P[j] = prev[((size_t)bc * NST + g * NPG + j) * DIM + dd];
    __syncthreads();

    float a_cur = bf2f(Abarb[(size_t)t0 * DIM + dd]) + 1e-8f;
    float x_cur = bf2f(xbarb[(size_t)t0 * DIM + dd]);
    for (int i = 0; i < SUB; ++i) {
        int t = t0 + i;
        float a_nxt = 0.f, x_nxt = 0.f;
        if (i + 1 < SUB) {
            a_nxt = bf2f(Abarb[(size_t)(t + 1) * DIM + dd]) + 1e-8f;
            x_nxt = bf2f(xbarb[(size_t)(t + 1) * DIM + dd]);
        }
        float4 b0 = *(const float4*)&Bs[i][0];
        float4 b1 = *(const float4*)&Bs[i][4];
        float4 b2 = *(const float4*)&Bs[i][8];
        float4 b3 = *(const float4*)&Bs[i][12];
        float4 c0 = *(const float4*)&Cs[i][0];
        float4 c1 = *(const float4*)&Cs[i][4];
        float4 c2 = *(const float4*)&Cs[i][8];
        float4 c3 = *(const float4*)&Cs[i][12];
        float bb[NPG] = {b0.x,b0.y,b0.z,b0.w, b1.x,b1.y,b1.z,b1.w,
                         b2.x,b2.y,b2.z,b2.w, b3.x,b3.y,b3.z,b3.w};
        float cc[NPG] = {c0.x,c0.y,c0.z,c0.w, c1.x,c1.y,c1.z,c1.w,
                         c2.x,c2.y,c2.z,c2.w, c3.x,c3.y,c3.z,c3.w};
        float ya[4] = {0.f, 0.f, 0.f, 0.f};
        #pragma unroll
        for (int j = 0; j < NPG; ++j) {
            H[j] = fmaf(a_cur, H[j], bb[j] * x_cur);
            ya[j & 3] = fmaf(cc[j], H[j] + P[j], ya[j & 3]);
        }
        p_y[((size_t)g * TOK + t) * DIM + dd] = f2bf((ya[0] + ya[1]) + (ya[2] + ya[3]));
        a_cur = a_nxt; x_cur = x_nxt;
    }
}

// y_g = (sum of 4 bf16 partials) * silu(z)  -> bf16
__global__ __launch_bounds__(256)
void gate_kernel(const unsigned short* __restrict__ p_y,
                 const unsigned short* __restrict__ zarrb,
                 unsigned short* __restrict__ ygb)
{
    int v = blockIdx.x * 256 + threadIdx.x;
    if (v >= TOK * 48) return;
    int t = v / 48;
    int dd = (v % 48) * 4;
    const size_t Q = (size_t)TOK * DIM;
    size_t off = (size_t)t * DIM + dd;
    float acc[4] = {0.f, 0.f, 0.f, 0.f};
    #pragma unroll
    for (int gidx = 0; gidx < NG; ++gidx) {
        ushort4 y = *(const ushort4*)(p_y + off + (size_t)gidx * Q);
        acc[0] += bf2f(y.x); acc[1] += bf2f(y.y);
        acc[2] += bf2f(y.z); acc[3] += bf2f(y.w);
    }
    ushort4 zu = *(const ushort4*)(zarrb + off);
    float z0 = bf2f(zu.x), z1 = bf2f(zu.y), z2 = bf2f(zu.z), z3 = bf2f(zu.w);
    ushort4 r;
    r.x = f2bf(acc[0] * (z0 / (1.f + expf(-z0))));
    r.y = f2bf(acc[1] * (z1 / (1.f + expf(-z1))));
    r.z = f2bf(acc[2] * (z2 / (1.f + expf(-z2))));
    r.w = f2bf(acc[3] * (z3 / (1.f + expf(-z3))));
    *(ushort4*)(ygb + off) = r;
}

// ---------------------------------------------------------------------------
extern "C" void kernel_launch(void* const* d_in, const int* in_sizes, int n_in,
                              void* d_out, int out_size, void* d_ws, size_t ws_size,
                              hipStream_t stream)
{
    (void)in_sizes; (void)n_in; (void)out_size; (void)ws_size;
    const float* x     = (const float*)d_in[0];
    const float* A_log = (const float*)d_in[1];
    const float* W_B   = (const float*)d_in[2];
    const float* W_C   = (const float*)d_in[3];
    const float* W_dt  = (const float*)d_in[4];
    const float* b_dt  = (const float*)d_in[5];
    const float* W_xp  = (const float*)d_in[6];
    const float* b_xp  = (const float*)d_in[7];
    const float* W_out = (const float*)d_in[8];
    const float* b_out = (const float*)d_in[9];
    float* out = (float*)d_out;

    char* w = (char*)d_ws;
    auto take = [&](size_t bytes) { char* p = w; w += (bytes + 255) & ~(size_t)255; return p; };
    unsigned short* xb     = (unsigned short*)take((size_t)TOK*DIM*2);
    unsigned short* bigW   = (unsigned short*)take((size_t)704*DIM*2);
    unsigned short* woutb  = (unsigned short*)take((size_t)DIM*DIM*2);
    float*          biasAll= (float*)         take((size_t)704*4);
    unsigned short* xbarb  = (unsigned short*)take((size_t)TOK*DIM*2);
    unsigned short* zarrb  = (unsigned short*)take((size_t)TOK*DIM*2);
    float*          BC     = (float*)         take((size_t)TOK*128*4);
    unsigned short* Abarb  = (unsigned short*)take((size_t)TOK*DIM*2);
    float*          dprod  = (float*)         take((size_t)NCHUNKS*NSUB*DIM*4);
    float*          prev   = (float*)         take((size_t)NCHUNKS*NST*DIM*4);
    float*          Sarr   = (float*)         take((size_t)NCHUNKS*NSUB*NST*DIM*4);
    float*          Rarr   = (float*)         take((size_t)NCHUNKS*NSUB*NST*DIM*4);
    unsigned short* p_y    = (unsigned short*)take((size_t)NG*TOK*DIM*2);
    unsigned short* ygb    = (unsigned short*)take((size_t)TOK*DIM*2);

    dim3 blk(256);

    prep_kernel<<<dim3((PREP_N + 255)/256), blk, 0, stream>>>(
        x, W_xp, W_B, W_C, W_dt, W_out, b_xp, b_dt, xb, bigW, woutb, biasAll);
    gemm_all<<<dim3(TOK/128, 704/64), blk, 0, stream>>>(
        xb, bigW, biasAll, A_log, xbarb, zarrb, BC, Abarb);
    state_kernel<<<dim3(NCHUNKS, NSUB, NG), dim3(192), 0, stream>>>(
        xbarb, Abarb, BC, Sarr, Rarr, dprod);
    scan_kernel<<<dim3((BATCH*NST*48 + 255)/256), blk, 0, stream>>>(dprod, Rarr, prev);
    intra_kernel<<<dim3(NCHUNKS, NSUB, NG), dim3(192), 0, stream>>>(
        xbarb, Abarb, BC, prev, Sarr, dprod, p_y);
    gate_kernel<<<dim3((TOK*48 + 255)/256), blk, 0, stream>>>(p_y, zarrb, ygb);
    out_gemm<<<dim3(TOK/64, DIM/64), blk, 0, stream>>>(ygb, woutb, b_out, out);
}